// Round 3
// baseline (1958.419 us; speedup 1.0000x reference)
//
#include <hip/hip_runtime.h>
#include <hip/hip_fp16.h>

typedef _Float16 half8 __attribute__((ext_vector_type(8)));
typedef _Float16 half4 __attribute__((ext_vector_type(4)));
typedef float floatx4 __attribute__((ext_vector_type(4)));
typedef float fvec4 __attribute__((ext_vector_type(4)));

#define BB 4096
#define SS 50
#define HH 256
#define ROWS 32            // batch rows per block (2 MFMA M-tiles)
#define APAD 264           // LDS row stride in halfs (528 B, 16B aligned)

// ---- phase 0: convert W_ih / W_hh fp32 -> fp16 into workspace ----
__global__ void cvt_w(const float* __restrict__ wih,
                      const float* __restrict__ whh,
                      _Float16* __restrict__ ws) {
    int idx = (blockIdx.x * 256 + threadIdx.x) * 4;   // 4 floats per thread
    const int half1 = 768 * 256;                      // 196608
    const float* src = (idx < half1) ? (wih + idx) : (whh + (idx - half1));
    fvec4 v = *(const fvec4*)src;
    half4 h;
    h[0] = (_Float16)v.x; h[1] = (_Float16)v.y;
    h[2] = (_Float16)v.z; h[3] = (_Float16)v.w;
    *(half4*)(ws + idx) = h;
}

// ---- fused GRU scan: one block = 32 batch rows, all 50 steps ----
__global__ __launch_bounds__(512, 1) void gru_scan(
    const float* __restrict__ C, const float* __restrict__ G,
    const _Float16* __restrict__ Wih, const _Float16* __restrict__ Whh,
    const float* __restrict__ bih, const float* __restrict__ bhh,
    float* __restrict__ out)
{
    __shared__ _Float16 cA[ROWS * APAD];       // C_s tile, A-ready row-major f16
    __shared__ _Float16 hA[2][ROWS * APAD];    // h tile, double-buffered
    __shared__ float gS[ROWS];

    const int tid  = threadIdx.x;
    const int wave = tid >> 6;               // 0..7, owns h-cols [32w,32w+32)
    const int lane = tid & 63;
    const int q    = lane >> 4;              // quad 0..3
    const int c    = lane & 15;              // A: row m; B: col n; D: col n
    const int rb   = blockIdx.x * ROWS;

    // biases: gate g in {r,z,n}, sub-tile t in {0,1}; col = g*256 + wave*32 + t*16 + c
    float bi[3][2], bh[3][2];
#pragma unroll
    for (int g = 0; g < 3; ++g)
#pragma unroll
        for (int t = 0; t < 2; ++t) {
            int n = g * 256 + wave * 32 + t * 16 + c;
            bi[g][t] = bih[n];
            bh[g][t] = bhh[n];
        }

    // per-lane weight fragment base pointers (stationary across steps)
    const _Float16* wiP[3][2];
    const _Float16* whP[3][2];
#pragma unroll
    for (int g = 0; g < 3; ++g)
#pragma unroll
        for (int t = 0; t < 2; ++t) {
            int n0 = g * 256 + wave * 32 + t * 16;
            wiP[g][t] = Wih + (size_t)(n0 + c) * HH + q * 8;
            whP[g][t] = Whh + (size_t)(n0 + c) * HH + q * 8;
        }

    // persistent h, fp32, D-layout: hreg[mt][t][r] -> row mt*16+q*4+r, col wave*32+t*16+c
    float hreg[2][2][4];
#pragma unroll
    for (int mt = 0; mt < 2; ++mt)
#pragma unroll
        for (int t = 0; t < 2; ++t)
#pragma unroll
            for (int r = 0; r < 4; ++r) hreg[mt][t][r] = 0.f;

    for (int i = tid; i < ROWS * APAD; i += 512) hA[0][i] = (_Float16)0.f;

    // staging mapping: 512 threads cover 32 rows x 16 chunk-pairs of 8 floats
    const int m_st = tid & 31;
    const int ch   = tid >> 5;               // 0..15
    const float* crow = C + (size_t)(rb + m_st) * (SS * HH) + ch * 8;

    // prefetch s = 0 (nontemporal: C is stream-once, keep weights in L2)
    fvec4 pf0, pf1, pf2, pf3;
    float gpf = 0.f;
    {
        const fvec4* p  = (const fvec4*)(crow);
        const fvec4* p2 = (const fvec4*)(crow + 128);
        pf0 = __builtin_nontemporal_load(p);
        pf1 = __builtin_nontemporal_load(p + 1);
        pf2 = __builtin_nontemporal_load(p2);
        pf3 = __builtin_nontemporal_load(p2 + 1);
        if (tid < ROWS) gpf = __builtin_nontemporal_load(G + (size_t)(rb + tid) * SS);
    }
    __syncthreads();   // hA[0] zero-init visible

    for (int s = 0; s < SS; ++s) {
        // ---- commit staged C[:, s, :] -> cA (f16), G[:, s] -> gS ----
        {
            half8 hv;
            hv[0] = (_Float16)pf0.x; hv[1] = (_Float16)pf0.y;
            hv[2] = (_Float16)pf0.z; hv[3] = (_Float16)pf0.w;
            hv[4] = (_Float16)pf1.x; hv[5] = (_Float16)pf1.y;
            hv[6] = (_Float16)pf1.z; hv[7] = (_Float16)pf1.w;
            *(half8*)&cA[m_st * APAD + ch * 8] = hv;
            half8 hw;
            hw[0] = (_Float16)pf2.x; hw[1] = (_Float16)pf2.y;
            hw[2] = (_Float16)pf2.z; hw[3] = (_Float16)pf2.w;
            hw[4] = (_Float16)pf3.x; hw[5] = (_Float16)pf3.y;
            hw[6] = (_Float16)pf3.z; hw[7] = (_Float16)pf3.w;
            *(half8*)&cA[m_st * APAD + 128 + ch * 8] = hw;
            if (tid < ROWS) gS[tid] = gpf;
        }
        __syncthreads();

        // ---- prefetch next step's C/G while MFMAs run ----
        if (s + 1 < SS) {
            const fvec4* p  = (const fvec4*)(crow + (size_t)(s + 1) * HH);
            const fvec4* p2 = (const fvec4*)(crow + (size_t)(s + 1) * HH + 128);
            pf0 = __builtin_nontemporal_load(p);
            pf1 = __builtin_nontemporal_load(p + 1);
            pf2 = __builtin_nontemporal_load(p2);
            pf3 = __builtin_nontemporal_load(p2 + 1);
            if (tid < ROWS) gpf = __builtin_nontemporal_load(G + (size_t)(rb + tid) * SS + s + 1);
        }

        const _Float16* hAr = hA[s & 1];

        floatx4 acc_i[3][2][2], acc_h[3][2][2];   // [g][t][mt]
#pragma unroll
        for (int g = 0; g < 3; ++g)
#pragma unroll
            for (int t = 0; t < 2; ++t)
#pragma unroll
                for (int mt = 0; mt < 2; ++mt) {
                    acc_i[g][t][mt] = (floatx4){0.f, 0.f, 0.f, 0.f};
                    acc_h[g][t][mt] = (floatx4){0.f, 0.f, 0.f, 0.f};
                }

        // ---- K loop: each weight fragment feeds 2 M-tiles ----
#pragma unroll
        for (int kt = 0; kt < 8; ++kt) {
            half8 aC0 = *(const half8*)&cA[(c)      * APAD + kt * 32 + q * 8];
            half8 aC1 = *(const half8*)&cA[(16 + c) * APAD + kt * 32 + q * 8];
            half8 aH0 = *(const half8*)&hAr[(c)      * APAD + kt * 32 + q * 8];
            half8 aH1 = *(const half8*)&hAr[(16 + c) * APAD + kt * 32 + q * 8];
#pragma unroll
            for (int g = 0; g < 3; ++g)
#pragma unroll
                for (int t = 0; t < 2; ++t) {
                    half8 bI = *(const half8*)(wiP[g][t] + kt * 32);
                    half8 bH = *(const half8*)(whP[g][t] + kt * 32);
                    acc_i[g][t][0] = __builtin_amdgcn_mfma_f32_16x16x32_f16(aC0, bI, acc_i[g][t][0], 0, 0, 0);
                    acc_i[g][t][1] = __builtin_amdgcn_mfma_f32_16x16x32_f16(aC1, bI, acc_i[g][t][1], 0, 0, 0);
                    acc_h[g][t][0] = __builtin_amdgcn_mfma_f32_16x16x32_f16(aH0, bH, acc_h[g][t][0], 0, 0, 0);
                    acc_h[g][t][1] = __builtin_amdgcn_mfma_f32_16x16x32_f16(aH1, bH, acc_h[g][t][1], 0, 0, 0);
                }
        }

        // ---- gates + h update (fp32), write next hA buffer ----
        _Float16* hAw = hA[(s + 1) & 1];
#pragma unroll
        for (int mt = 0; mt < 2; ++mt)
#pragma unroll
            for (int t = 0; t < 2; ++t)
#pragma unroll
                for (int r = 0; r < 4; ++r) {
                    int m = q * 4 + r;
                    float ir  = acc_i[0][t][mt][r] + bi[0][t];
                    float hr  = acc_h[0][t][mt][r] + bh[0][t];
                    float iz  = acc_i[1][t][mt][r] + bi[1][t];
                    float hz  = acc_h[1][t][mt][r] + bh[1][t];
                    float in_ = acc_i[2][t][mt][r] + bi[2][t];
                    float hn  = acc_h[2][t][mt][r] + bh[2][t];
                    float rg  = 1.f / (1.f + __expf(-(ir + hr)));
                    float zg  = 1.f / (1.f + __expf(-(iz + hz)));
                    float pre = in_ + rg * hn;
                    float ap  = fabsf(pre);
                    float e2  = __expf(-2.f * ap);
                    float th  = (1.f - e2) / (1.f + e2);
                    float ng  = (pre < 0.f) ? -th : th;
                    float hold = hreg[mt][t][r];
                    float hnew = (1.f - zg) * ng + zg * hold;
                    float gg   = gS[mt * 16 + m];
                    float hout = gg * hnew + (1.f - gg) * hold;
                    hreg[mt][t][r] = hout;
                    hAw[(mt * 16 + m) * APAD + wave * 32 + t * 16 + c] = (_Float16)hout;
                }
        __syncthreads();
    }

    // ---- write h_final (fp32) ----
#pragma unroll
    for (int mt = 0; mt < 2; ++mt)
#pragma unroll
        for (int t = 0; t < 2; ++t)
#pragma unroll
            for (int r = 0; r < 4; ++r) {
                int m = q * 4 + r;
                out[(size_t)(rb + mt * 16 + m) * HH + wave * 32 + t * 16 + c] = hreg[mt][t][r];
            }
}

extern "C" void kernel_launch(void* const* d_in, const int* in_sizes, int n_in,
                              void* d_out, int out_size, void* d_ws, size_t ws_size,
                              hipStream_t stream) {
    const float* C   = (const float*)d_in[0];
    const float* G   = (const float*)d_in[1];
    const float* Wih = (const float*)d_in[2];
    const float* Whh = (const float*)d_in[3];
    const float* bih = (const float*)d_in[4];
    const float* bhh = (const float*)d_in[5];
    _Float16* wsh = (_Float16*)d_ws;   // [0,196608): W_ih f16; [196608,393216): W_hh f16

    cvt_w<<<384, 256, 0, stream>>>(Wih, Whh, wsh);
    gru_scan<<<BB / ROWS, 512, 0, stream>>>(C, G, wsh, wsh + 768 * 256,
                                            bih, bhh, (float*)d_out);
}

// Round 4
// 1299.747 us; speedup vs baseline: 1.5068x; 1.5068x over previous
//
#include <hip/hip_runtime.h>
#include <hip/hip_fp16.h>

typedef _Float16 half8 __attribute__((ext_vector_type(8)));
typedef _Float16 half4 __attribute__((ext_vector_type(4)));
typedef float floatx4 __attribute__((ext_vector_type(4)));
typedef float fvec4 __attribute__((ext_vector_type(4)));

#define SS 50
#define HH 256
#define APAD 264               // LDS row stride in halfs (528 B, 16B aligned, breaks pow2)
#define WHALF (768 * 256)      // halfs per weight matrix

__device__ __forceinline__ float sigm(float x) { return 1.f / (1.f + __expf(-x)); }
__device__ __forceinline__ float tanh_f(float x) {
    float ap = fabsf(x);
    float e2 = __expf(-2.f * ap);
    float th = (1.f - e2) / (1.f + e2);
    return (x < 0.f) ? -th : th;
}

// ---- phase 0: convert W_ih / W_hh fp32 -> fp16 into workspace ----
__global__ void cvt_w(const float* __restrict__ wih,
                      const float* __restrict__ whh,
                      _Float16* __restrict__ ws) {
    int idx = (blockIdx.x * 256 + threadIdx.x) * 4;
    const float* src = (idx < WHALF) ? (wih + idx) : (whh + (idx - WHALF));
    fvec4 v = *(const fvec4*)src;
    half4 h;
    h[0] = (_Float16)v.x; h[1] = (_Float16)v.y;
    h[2] = (_Float16)v.z; h[3] = (_Float16)v.w;
    *(half4*)(ws + idx) = h;
}

// ---- persistent fused kernel: chunks of (gi GEMM phase -> scan phase) ----
// block = 16 batch rows, wave w owns h-cols [32w,32w+32). Weights live in 192 VGPRs.
__global__ __launch_bounds__(512, 2) void gru_all(
    const float* __restrict__ C, const float* __restrict__ G,
    const float* __restrict__ bih, const float* __restrict__ bhh,
    const _Float16* __restrict__ Wf, _Float16* __restrict__ giws,
    float* __restrict__ out, int Sc)
{
    __shared__ _Float16 cA[2][16 * APAD];   // C staging (gi phase), double-buffered
    __shared__ _Float16 hA[2][16 * APAD];   // h f16 round-trip (scan phase)

    const int tid  = threadIdx.x;
    const int w    = tid >> 6;
    const int lane = tid & 63;
    const int q    = lane >> 4;
    const int c    = lane & 15;
    const int rb   = blockIdx.x * 16;

    const _Float16* Wih = Wf;
    const _Float16* Whh = Wf + WHALF;

    // biases: bi (+ bh for r,z gates) folded into gi at store time; bh_n kept separate
    float bsum[6], bhn[2];
#pragma unroll
    for (int t2 = 0; t2 < 6; ++t2) {
        int g = t2 >> 1, t = t2 & 1;
        int n = g * 256 + w * 32 + t * 16 + c;
        bsum[t2] = bih[n] + (g < 2 ? bhh[n] : 0.f);
    }
#pragma unroll
    for (int t = 0; t < 2; ++t) bhn[t] = bhh[512 + w * 32 + t * 16 + c];

    float hreg[2][4];
#pragma unroll
    for (int t = 0; t < 2; ++t)
#pragma unroll
        for (int r = 0; r < 4; ++r) hreg[t][r] = 0.f;

    for (int i = tid; i < 16 * APAD; i += 512) hA[0][i] = (_Float16)0.f;

    const int m_st = tid & 15;
    const int chk  = tid >> 4;             // 0..31, 8 floats each
    const float* crow = C + (size_t)(rb + m_st) * (SS * HH) + chk * 8;
    _Float16* giB = giws + (size_t)blockIdx.x * Sc * 12288 + tid * 24;

    half8 wf[6][8];                        // 192 VGPRs of weight fragments
    int hp = 0;
    const int nch = (SS + Sc - 1) / Sc;

    for (int cc = 0; cc < nch; ++cc) {
        const int s0  = cc * Sc;
        const int Scc = (Sc < SS - s0) ? Sc : (SS - s0);

        // ======== gi phase: W_ih resident ========
#pragma unroll
        for (int t2 = 0; t2 < 6; ++t2) {
            const _Float16* base = Wih +
                (size_t)(((t2 >> 1) * 256 + w * 32 + (t2 & 1) * 16) + c) * HH + q * 8;
#pragma unroll
            for (int kt = 0; kt < 8; ++kt) wf[t2][kt] = *(const half8*)(base + kt * 32);
        }
        fvec4 cf0 = __builtin_nontemporal_load((const fvec4*)(crow + (size_t)s0 * HH));
        fvec4 cf1 = __builtin_nontemporal_load((const fvec4*)(crow + (size_t)s0 * HH + 4));

        for (int sc = 0; sc < Scc; ++sc) {
            const int s = s0 + sc;
            {
                half8 hv;
                hv[0] = (_Float16)cf0.x; hv[1] = (_Float16)cf0.y;
                hv[2] = (_Float16)cf0.z; hv[3] = (_Float16)cf0.w;
                hv[4] = (_Float16)cf1.x; hv[5] = (_Float16)cf1.y;
                hv[6] = (_Float16)cf1.z; hv[7] = (_Float16)cf1.w;
                *(half8*)&cA[sc & 1][m_st * APAD + chk * 8] = hv;
            }
            __syncthreads();
            if (sc + 1 < Scc) {
                cf0 = __builtin_nontemporal_load((const fvec4*)(crow + (size_t)(s + 1) * HH));
                cf1 = __builtin_nontemporal_load((const fvec4*)(crow + (size_t)(s + 1) * HH + 4));
            }
            floatx4 acc[6];
#pragma unroll
            for (int t2 = 0; t2 < 6; ++t2) acc[t2] = (floatx4){0.f, 0.f, 0.f, 0.f};
#pragma unroll
            for (int kt = 0; kt < 8; ++kt) {
                half8 a = *(const half8*)&cA[sc & 1][c * APAD + kt * 32 + q * 8];
#pragma unroll
                for (int t2 = 0; t2 < 6; ++t2)
                    acc[t2] = __builtin_amdgcn_mfma_f32_16x16x32_f16(a, wf[t2][kt], acc[t2], 0, 0, 0);
            }
            // store gi (+biases) lane-matched: 24 halfs = 48 B per thread
            half8 o[3];
#pragma unroll
            for (int t2 = 0; t2 < 6; ++t2)
#pragma unroll
                for (int r = 0; r < 4; ++r) {
                    int idx = t2 * 4 + r;
                    o[idx >> 3][idx & 7] = (_Float16)(acc[t2][r] + bsum[t2]);
                }
            _Float16* gp = giB + (size_t)sc * 12288;
            *(half8*)gp        = o[0];
            *(half8*)(gp + 8)  = o[1];
            *(half8*)(gp + 16) = o[2];
        }

        // ======== scan phase: W_hh resident ========
#pragma unroll
        for (int t2 = 0; t2 < 6; ++t2) {
            const _Float16* base = Whh +
                (size_t)(((t2 >> 1) * 256 + w * 32 + (t2 & 1) * 16) + c) * HH + q * 8;
#pragma unroll
            for (int kt = 0; kt < 8; ++kt) wf[t2][kt] = *(const half8*)(base + kt * 32);
        }

        for (int sc = 0; sc < Scc; ++sc) {
            const int s = s0 + sc;
            __syncthreads();   // hA[hp] ready; also drains gi stores on first iter
            const _Float16* gp = giB + (size_t)sc * 12288;
            half8 g0 = *(const half8*)gp;
            half8 g1 = *(const half8*)(gp + 8);
            half8 g2 = *(const half8*)(gp + 16);
            float gv[4];
#pragma unroll
            for (int r = 0; r < 4; ++r) gv[r] = G[(size_t)(rb + q * 4 + r) * SS + s];

            floatx4 acch[6];
#pragma unroll
            for (int t2 = 0; t2 < 6; ++t2) acch[t2] = (floatx4){0.f, 0.f, 0.f, 0.f};
#pragma unroll
            for (int kt = 0; kt < 8; ++kt) {
                half8 a = *(const half8*)&hA[hp][c * APAD + kt * 32 + q * 8];
#pragma unroll
                for (int t2 = 0; t2 < 6; ++t2)
                    acch[t2] = __builtin_amdgcn_mfma_f32_16x16x32_f16(a, wf[t2][kt], acch[t2], 0, 0, 0);
            }

            float gif[24];
#pragma unroll
            for (int idx = 0; idx < 24; ++idx)
                gif[idx] = (float)((idx < 8) ? g0[idx] : (idx < 16) ? g1[idx - 8] : g2[idx - 16]);

            _Float16* hw = hA[hp ^ 1];
#pragma unroll
            for (int t = 0; t < 2; ++t)
#pragma unroll
                for (int r = 0; r < 4; ++r) {
                    float i_r = gif[(0 * 2 + t) * 4 + r];
                    float i_z = gif[(1 * 2 + t) * 4 + r];
                    float i_n = gif[(2 * 2 + t) * 4 + r];
                    float h_r = acch[0 * 2 + t][r];
                    float h_z = acch[1 * 2 + t][r];
                    float h_n = acch[2 * 2 + t][r] + bhn[t];
                    float rg = sigm(i_r + h_r);
                    float zg = sigm(i_z + h_z);
                    float ng = tanh_f(i_n + rg * h_n);
                    float hold = hreg[t][r];
                    float hnew = (1.f - zg) * ng + zg * hold;
                    float gg = gv[r];
                    float hout = gg * hnew + (1.f - gg) * hold;
                    hreg[t][r] = hout;
                    hw[(q * 4 + r) * APAD + w * 32 + t * 16 + c] = (_Float16)hout;
                }
            hp ^= 1;
        }
    }

#pragma unroll
    for (int t = 0; t < 2; ++t)
#pragma unroll
        for (int r = 0; r < 4; ++r)
            out[(size_t)(rb + q * 4 + r) * HH + w * 32 + t * 16 + c] = hreg[t][r];
}

// ---- fallback (R1 kernel): used only if ws too small for gi staging ----
__global__ __launch_bounds__(512, 2) void gru_fused(
    const float* __restrict__ C, const float* __restrict__ G,
    const _Float16* __restrict__ Wih, const _Float16* __restrict__ Whh,
    const float* __restrict__ bih, const float* __restrict__ bhh,
    float* __restrict__ out)
{
    __shared__ _Float16 cA[16 * APAD];
    __shared__ _Float16 hA[2][16 * APAD];
    __shared__ float gS[16];
    const int tid = threadIdx.x, wave = tid >> 6, lane = tid & 63;
    const int q = lane >> 4, c = lane & 15, rb = blockIdx.x * 16;
    float bi[3][2], bh[3][2];
#pragma unroll
    for (int g = 0; g < 3; ++g)
#pragma unroll
        for (int t = 0; t < 2; ++t) {
            int n = g * 256 + wave * 32 + t * 16 + c;
            bi[g][t] = bih[n]; bh[g][t] = bhh[n];
        }
    const _Float16 *wiP[3][2], *whP[3][2];
#pragma unroll
    for (int g = 0; g < 3; ++g)
#pragma unroll
        for (int t = 0; t < 2; ++t) {
            int n0 = g * 256 + wave * 32 + t * 16;
            wiP[g][t] = Wih + (size_t)(n0 + c) * HH + q * 8;
            whP[g][t] = Whh + (size_t)(n0 + c) * HH + q * 8;
        }
    float hreg[2][4];
#pragma unroll
    for (int t = 0; t < 2; ++t)
#pragma unroll
        for (int r = 0; r < 4; ++r) hreg[t][r] = 0.f;
    for (int i = tid; i < 16 * APAD; i += 512) hA[0][i] = (_Float16)0.f;
    __syncthreads();
    const int m_st = tid & 15, ch = tid >> 4;
    const float* crow = C + (size_t)(rb + m_st) * (SS * HH) + ch * 8;
    for (int s = 0; s < SS; ++s) {
        {
            fvec4 v0 = *(const fvec4*)(crow + (size_t)s * HH);
            fvec4 v1 = *(const fvec4*)(crow + (size_t)s * HH + 4);
            half8 hv;
            hv[0] = (_Float16)v0.x; hv[1] = (_Float16)v0.y;
            hv[2] = (_Float16)v0.z; hv[3] = (_Float16)v0.w;
            hv[4] = (_Float16)v1.x; hv[5] = (_Float16)v1.y;
            hv[6] = (_Float16)v1.z; hv[7] = (_Float16)v1.w;
            *(half8*)&cA[m_st * APAD + ch * 8] = hv;
            if (tid < 16) gS[tid] = G[(size_t)(rb + tid) * SS + s];
        }
        __syncthreads();
        const _Float16* hAr = hA[s & 1];
        floatx4 acc_i[3][2], acc_h[3][2];
#pragma unroll
        for (int g = 0; g < 3; ++g)
#pragma unroll
            for (int t = 0; t < 2; ++t) {
                acc_i[g][t] = (floatx4){0.f, 0.f, 0.f, 0.f};
                acc_h[g][t] = (floatx4){0.f, 0.f, 0.f, 0.f};
            }
#pragma unroll
        for (int kt = 0; kt < 8; ++kt) {
            half8 aC = *(const half8*)&cA[c * APAD + kt * 32 + q * 8];
            half8 aH = *(const half8*)&hAr[c * APAD + kt * 32 + q * 8];
#pragma unroll
            for (int g = 0; g < 3; ++g)
#pragma unroll
                for (int t = 0; t < 2; ++t) {
                    half8 bI = *(const half8*)(wiP[g][t] + kt * 32);
                    half8 bH = *(const half8*)(whP[g][t] + kt * 32);
                    acc_i[g][t] = __builtin_amdgcn_mfma_f32_16x16x32_f16(aC, bI, acc_i[g][t], 0, 0, 0);
                    acc_h[g][t] = __builtin_amdgcn_mfma_f32_16x16x32_f16(aH, bH, acc_h[g][t], 0, 0, 0);
                }
        }
        _Float16* hAw = hA[(s + 1) & 1];
#pragma unroll
        for (int t = 0; t < 2; ++t)
#pragma unroll
            for (int r = 0; r < 4; ++r) {
                int m = q * 4 + r;
                float rg = sigm(acc_i[0][t][r] + bi[0][t] + acc_h[0][t][r] + bh[0][t]);
                float zg = sigm(acc_i[1][t][r] + bi[1][t] + acc_h[1][t][r] + bh[1][t]);
                float ng = tanh_f(acc_i[2][t][r] + bi[2][t] + rg * (acc_h[2][t][r] + bh[2][t]));
                float hold = hreg[t][r];
                float hnew = (1.f - zg) * ng + zg * hold;
                float gg = gS[m];
                float hout = gg * hnew + (1.f - gg) * hold;
                hreg[t][r] = hout;
                hAw[m * APAD + wave * 32 + t * 16 + c] = (_Float16)hout;
            }
        __syncthreads();
    }
#pragma unroll
    for (int t = 0; t < 2; ++t)
#pragma unroll
        for (int r = 0; r < 4; ++r)
            out[(size_t)(rb + q * 4 + r) * HH + wave * 32 + t * 16 + c] = hreg[t][r];
}

extern "C" void kernel_launch(void* const* d_in, const int* in_sizes, int n_in,
                              void* d_out, int out_size, void* d_ws, size_t ws_size,
                              hipStream_t stream) {
    const float* C   = (const float*)d_in[0];
    const float* G   = (const float*)d_in[1];
    const float* Wih = (const float*)d_in[2];
    const float* Whh = (const float*)d_in[3];
    const float* bih = (const float*)d_in[4];
    const float* bhh = (const float*)d_in[5];
    _Float16* wsh = (_Float16*)d_ws;            // f16 weights: 786432 bytes
    const size_t wbytes = (size_t)WHALF * 2 * 2;
    const size_t per_sc = (size_t)256 * 512 * 24 * 2;   // 6291456 B per step (all blocks)
    size_t avail = ws_size > wbytes ? ws_size - wbytes : 0;
    long Sc_l = (long)(avail / per_sc);
    int Sc = Sc_l > 50 ? 50 : (int)Sc_l;

    cvt_w<<<384, 256, 0, stream>>>(Wih, Whh, wsh);
    if (Sc >= 1) {
        gru_all<<<256, 512, 0, stream>>>(C, G, bih, bhh, wsh,
                                         wsh + (size_t)WHALF * 2, (float*)d_out, Sc);
    } else {
        gru_fused<<<256, 512, 0, stream>>>(C, G, wsh, wsh + WHALF,
                                           bih, bhh, (float*)d_out);
    }
}